// Round 11
// baseline (269.605 us; speedup 1.0000x reference)
//
#include <hip/hip_runtime.h>
#include <cstdint>
#include <cstddef>

// Problem constants: B=4, S=2048, D=1024, H=4096, M = B*S = 8192.
#define MROWS 8192
#define DDIM  1024
#define HDIM  4096

typedef __bf16 bf16x8 __attribute__((ext_vector_type(8)));
typedef float  f32x4  __attribute__((ext_vector_type(4)));

typedef __attribute__((address_space(1))) void* as1_vp;
typedef __attribute__((address_space(3))) void* as3_vp;

__device__ __forceinline__ unsigned short f2bf(float f) {
  unsigned int u = __builtin_bit_cast(unsigned int, f);
  u += 0x7fffu + ((u >> 16) & 1u);   // RNE
  return (unsigned short)(u >> 16);
}

// fast gelu: tanh-form, exp2+rcp based. |err vs exact erf-gelu| < ~1e-3.
__device__ __forceinline__ float fast_gelu(float x) {
  float x3 = x * x * x;
  float z = 0.7978845608028654f * x + 0.03567740814f * x3;
  float e = __builtin_amdgcn_exp2f(z * 2.8853900817779268f); // exp(2z)
  float t = 1.0f - 2.0f * __builtin_amdgcn_rcpf(e + 1.0f);   // tanh(z)
  return 0.5f * x * (1.0f + t);
}

__device__ __forceinline__ void gld_lds16(const unsigned short* g, unsigned short* lds) {
  __builtin_amdgcn_global_load_lds((as1_vp)(uintptr_t)g, (as3_vp)lds, 16, 0, 0);
}

#define VMW(n)  asm volatile("s_waitcnt vmcnt(" #n ")" ::: "memory")
#define LKW()   asm volatile("s_waitcnt lgkmcnt(0)" ::: "memory")
#define BAR()   asm volatile("s_barrier" ::: "memory")

// pre_kernel v2 (R9): grid 2560. Blocks [0,2048): p1 + xb emit.
// Blocks [2048,2560): W1,W2 fp32->bf16, 16 float4/thread fully unrolled.
__global__ __launch_bounds__(256) void pre_kernel(
    const float* __restrict__ x, const float* __restrict__ w1,
    const float* __restrict__ w2, unsigned short* __restrict__ xb,
    unsigned short* __restrict__ w1b, unsigned short* __restrict__ w2b,
    float* __restrict__ p1) {
  if (blockIdx.x >= 2048) {
    const int j = blockIdx.x - 2048;           // 0..511
    const float4* src; ushort4* dst; int off0;
    if (j < 256) { src = (const float4*)w1; dst = (ushort4*)w1b; off0 = j * 4096 + threadIdx.x; }
    else         { src = (const float4*)w2; dst = (ushort4*)w2b; off0 = (j - 256) * 4096 + threadIdx.x; }
    float4 v[16];
#pragma unroll
    for (int k = 0; k < 16; ++k) v[k] = src[off0 + k * 256];
#pragma unroll
    for (int k = 0; k < 16; ++k) {
      ushort4 o;
      o.x = f2bf(v[k].x); o.y = f2bf(v[k].y); o.z = f2bf(v[k].z); o.w = f2bf(v[k].w);
      dst[off0 + k * 256] = o;
    }
    return;
  }
  const int bid = blockIdx.x;                  // 0..2047
  const int wave = threadIdx.x >> 6, lane = threadIdx.x & 63;
  const int m = bid * 4 + wave;
  const int b = m >> 11;
  const float4* xrow4 = (const float4*)(x + (size_t)m * DDIM);
  const float4* od4   = (const float4*)(x + ((size_t)b * 2048 + 2) * DDIM);
  ushort4* xbrow4 = (ushort4*)(xb + (size_t)m * DDIM);
  float a0 = 0.f, a1 = 0.f, a2 = 0.f, a3 = 0.f;
#pragma unroll
  for (int it = 0; it < 4; ++it) {
    int g = it * 64 + lane;
    float4 v = xrow4[g];
    ushort4 o; o.x = f2bf(v.x); o.y = f2bf(v.y); o.z = f2bf(v.z); o.w = f2bf(v.w);
    xbrow4[g] = o;
    float4 o0 = od4[g];
    float4 o1 = od4[512 + g];
    float4 o2 = od4[1024 + g];
    float4 o3 = od4[1536 + g];
    a0 += v.x * o0.x + v.y * o0.y + v.z * o0.z + v.w * o0.w;
    a1 += v.x * o1.x + v.y * o1.y + v.z * o1.z + v.w * o1.w;
    a2 += v.x * o2.x + v.y * o2.y + v.z * o2.z + v.w * o2.w;
    a3 += v.x * o3.x + v.y * o3.y + v.z * o3.z + v.w * o3.w;
  }
#pragma unroll
  for (int off = 32; off > 0; off >>= 1) {
    a0 += __shfl_down(a0, off);
    a1 += __shfl_down(a1, off);
    a2 += __shfl_down(a2, off);
    a3 += __shfl_down(a3, off);
  }
  if (lane == 0) {
    float4 r; r.x = a0; r.y = a1; r.z = a2; r.w = a3;
    ((float4*)p1)[m] = r;
  }
}

// ---------------------------------------------------------------------------
// GEMM1 v8 (fixed name collision: frag sets bP/bQ, NOT b0/b1 — b1 is the
// bias kernel param): B-DIRECT. 256x256, BK=32, 8 waves 2Mx4N.
// A: LDS ring-4 x 16KB = 64KB (proven-zero rotation swizzle, 2 gld_lds/thr).
// B: register fragments loaded DIRECTLY from global (w1b, L2/L3-hot), 2 sets
//   ping-pong, 1 tile ahead. Removes B from the per-CU LDS port (R9 model:
//   port 37us -> ~24us, now under the 34us MFMA floor).
// Per body t (steady):
//   VMW(2)                      // confirms G(t) + all older (S(t+1) etc.)
//   LKW; MFA(a03(t), bp(t))     // 16 MFMA
//   RB47: a47 <- LDS buf t&3    // 4 ds_reads
//   G_B(t+1 -> other B set)     // 4 global b128 (offset:imm)
//   S_A(t+3 -> buf (t+3)&3)     // 2 gld_lds
//   LKW; MFB(bp(t))             // 16 MFMA (a47 retired by LKW)
//   BAR                         // publishes S(t+1); WAR-gate for buf (t-1)&3
//   RA03(buf (t+1)&3 -> other a03 set)   // 4 ds_reads
// vmcnt ledger (issue order per body: G then S): entering body t outstanding =
//  [G(t)(4), S(t+2)(2)]; VMW(2) -> confirms G(t) and everything older.
// WAR: S_A(t+3) hits buf (t-1)&3; its readers retired via LKW before body
//  t-1's BAR < this issue. Tail uses VMW(0) (drain is tail-only).
// ---------------------------------------------------------------------------
__global__ __launch_bounds__(512, 1) void gemm1_kernel(
    const unsigned short* __restrict__ xb, const unsigned short* __restrict__ w1b,
    const float* __restrict__ x, const float* __restrict__ b1,
    const float* __restrict__ p1, const float* __restrict__ scale_p,
    unsigned short* __restrict__ hact) {
  __shared__ __align__(16) unsigned short As[4 * 8192];   // 64 KB, A only

  const int id = blockIdx.x;                 // 512 blocks
  const int xcd = id & 7, w = id >> 3;       // XCD-contiguous m-bands
  const int m0 = (xcd * 4 + (w & 3)) * 256;  // 32 m-tiles
  const int n0 = (w >> 2) * 256;             // 16 n-tiles

  const int tid  = threadIdx.x;
  const int wave = tid >> 6, lane = tid & 63;
  const int quad = lane >> 4, l16 = lane & 15;
  const int wm2  = wave >> 2;                // 0..1 -> 128-row half
  const int wn2  = wave & 3;                 // 0..3 -> 64-col slice

  // A stage pointers (2 slots/thread; rotation swizzle via global source).
  const unsigned short *gA0, *gA1;
  {
    int idx = tid;
    int r = idx >> 2, sl = idx & 3, c = (sl - (r >> 1)) & 3;
    gA0 = xb + (size_t)(m0 + r) * DDIM + c * 8;
    idx = 512 + tid;
    r = idx >> 2; sl = idx & 3; c = (sl - (r >> 1)) & 3;
    gA1 = xb + (size_t)(m0 + r) * DDIM + c * 8;
  }
  const int ldsOff0 = (wave * 64) * 8;
  const int ldsOff1 = (512 + wave * 64) * 8;

#define STG_A(tt, sb) do {                                    \
    const int _k = (tt) * 32;                                 \
    unsigned short* _a = As + (sb) * 8192;                    \
    gld_lds16(gA0 + _k, _a + ldsOff0);                        \
    gld_lds16(gA1 + _k, _a + ldsOff1);                        \
  } while (0)

  // B fragment base pointers: frag j covers rows n0+wn2*64+j*16+l16,
  // k-bytes quad*16 within each 2KB row. Per-tile offset = t*32 halfwords.
  const unsigned short* gB[4];
#pragma unroll
  for (int j = 0; j < 4; ++j)
    gB[j] = w1b + (size_t)(n0 + wn2 * 64 + j * 16 + l16) * DDIM + quad * 8;

#define G_B(tt, bs) do {                                      \
    bs[0] = *(const bf16x8*)(gB[0] + (tt) * 32);              \
    bs[1] = *(const bf16x8*)(gB[1] + (tt) * 32);              \
    bs[2] = *(const bf16x8*)(gB[2] + (tt) * 32);              \
    bs[3] = *(const bf16x8*)(gB[3] + (tt) * 32);              \
  } while (0)

  f32x4 acc[8][4];
  const f32x4 z = {0.f, 0.f, 0.f, 0.f};
#pragma unroll
  for (int i = 0; i < 8; ++i)
#pragma unroll
    for (int j = 0; j < 4; ++j) acc[i][j] = z;

  bf16x8 a03A[4], a03B[4], a47[4];   // A frag sets (static-indexed, rule #20)
  bf16x8 bP[4], bQ[4];               // B ping-pong sets (renamed: b1 is bias!)

  auto RA03 = [&](int nb, bf16x8 (&aa)[4]) {
    const unsigned short* Ab = As + nb * 8192;
#pragma unroll
    for (int i = 0; i < 4; ++i) {
      const int ra = wm2 * 128 + i * 16 + l16;
      aa[i] = *(const bf16x8*)(Ab + ra * 32 + ((quad + (ra >> 1)) & 3) * 8);
    }
  };
  auto RB47 = [&](int cb) {
    const unsigned short* Ab = As + cb * 8192;
#pragma unroll
    for (int i = 0; i < 4; ++i) {
      const int ra = wm2 * 128 + (i + 4) * 16 + l16;
      a47[i] = *(const bf16x8*)(Ab + ra * 32 + ((quad + (ra >> 1)) & 3) * 8);
    }
  };
  auto MFA = [&](bf16x8 (&aa)[4], bf16x8 (&bs)[4]) {
    __builtin_amdgcn_s_setprio(1);
#pragma unroll
    for (int i = 0; i < 4; ++i)
#pragma unroll
      for (int j = 0; j < 4; ++j)
        acc[i][j] = __builtin_amdgcn_mfma_f32_16x16x32_bf16(aa[i], bs[j], acc[i][j], 0, 0, 0);
    __builtin_amdgcn_s_setprio(0);
  };
  auto MFB = [&](bf16x8 (&bs)[4]) {
    __builtin_amdgcn_s_setprio(1);
#pragma unroll
    for (int i = 0; i < 4; ++i)
#pragma unroll
      for (int j = 0; j < 4; ++j)
        acc[4 + i][j] = __builtin_amdgcn_mfma_f32_16x16x32_bf16(a47[i], bs[j], acc[4 + i][j], 0, 0, 0);
    __builtin_amdgcn_s_setprio(0);
  };

#define BODY(tt, CB, SB, NB, ACUR, ANXT, BCUR, BNXT) do {     \
    VMW(2);                                                   \
    LKW(); MFA(a03##ACUR, BCUR);                              \
    RB47(CB);                                                 \
    G_B((tt) + 1, BNXT);                                      \
    STG_A((tt) + 3, SB);                                      \
    LKW(); MFB(BCUR);                                         \
    BAR();                                                    \
    RA03(NB, a03##ANXT);                                      \
  } while (0)

  // Prologue: S(0),S(1),G(0): VMW(4) confirms S0,S1 (G0 stays in flight);
  // BAR; read a03(0); then S(2) so entering-body-0 queue = [G0, S2].
  STG_A(0, 0);
  STG_A(1, 1);
  G_B(0, bP);
  VMW(4); BAR();
  RA03(0, a03A);
  STG_A(2, 2);

#pragma unroll 1
  for (int t = 0; t < 28; t += 4) {   // bodies 0..27, S up to 30, G up to 28
    BODY(t + 0, 0, 3, 1, A, B, bP, bQ);
    BODY(t + 1, 1, 0, 2, B, A, bQ, bP);
    BODY(t + 2, 2, 1, 3, A, B, bP, bQ);
    BODY(t + 3, 3, 2, 0, B, A, bQ, bP);
  }
  // body 28: normal (S(31) last stage, G(29)).
  BODY(28, 0, 3, 1, A, B, bP, bQ);
  // body 29: no S; G(30).
  VMW(2);
  LKW(); MFA(a03B, bQ);
  RB47(1);
  G_B(30, bP);
  LKW(); MFB(bQ);
  BAR();
  RA03(2, a03A);
  // body 30: no S; G(31). Drain (tail only).
  VMW(0);
  LKW(); MFA(a03A, bP);
  RB47(2);
  G_B(31, bQ);
  LKW(); MFB(bP);
  BAR();
  RA03(3, a03B);
  // body 31.
  VMW(0);
  LKW(); MFA(a03B, bQ);
  RB47(3);
  LKW(); MFB(bQ);

  // Epilogue: gelu( acc + b1 + scale*p1*even ), bf16 store to hact.
  const float sc = scale_p[0];
  const int bidx = m0 >> 11;
  const int i1 = (n0 + wn2 * 64) >> 10;      // wave-uniform lora index
  const float* exrow = x + ((size_t)(bidx * 2048 + 1 + 2 * i1)) * DDIM;

  float exv[4], b1v[4]; int nn[4];
#pragma unroll
  for (int j = 0; j < 4; ++j) {
    nn[j]  = n0 + wn2 * 64 + j * 16 + l16;
    exv[j] = exrow[nn[j] & 1023];
    b1v[j] = b1[nn[j]];
  }
#pragma unroll
  for (int i = 0; i < 8; ++i) {
#pragma unroll
    for (int r = 0; r < 4; ++r) {
      const int m = m0 + wm2 * 128 + i * 16 + quad * 4 + r;
      const float pv = p1[(size_t)m * 4 + i1] * sc;
#pragma unroll
      for (int j = 0; j < 4; ++j) {
        float v = acc[i][j][r] + b1v[j] + pv * exv[j];
        hact[(size_t)m * HDIM + nn[j]] = f2bf(fast_gelu(v));
      }
    }
  }
#undef BODY
#undef STG_A
#undef G_B
}

// ---------------------------------------------------------------------------
// GEMM2 (R4 structure, best measured 82.3us): 256m x 128n, BK=64, ring-3,
// rotated 2-phase body, counted VMW(6), 1 barrier/tile. p2 fused on matrix
// pipe (static-index wave-uniform selects — rule #20). Unchanged this round.
// ---------------------------------------------------------------------------
__global__ __launch_bounds__(512, 2) void gemm2_kernel(
    const unsigned short* __restrict__ hact, const unsigned short* __restrict__ w2b,
    const float* __restrict__ x, const float* __restrict__ b2,
    const float* __restrict__ scale_p, float* __restrict__ out) {
  __shared__ __align__(16) unsigned short As[3 * 256 * 64];   // 96 KB
  __shared__ __align__(16) unsigned short Bs[3 * 128 * 64];   // 48 KB
  __shared__ __align__(16) unsigned short od_lds[1024];       // 2 KB
  __shared__ __align__(16) float p2s[256 * 4];                // 4 KB

  const int id = blockIdx.x;                 // 256 blocks = 1/CU
  const int xcd = id & 7, w = id >> 3;       // 32 blocks per XCD
  const int m0 = (xcd * 4 + (w & 3)) * 256;  // 32 m-tiles
  const int n0 = (w >> 2) * 128;             // 8 n-tiles
  const int tid = threadIdx.x;
  const int wave = tid >> 6, lane = tid & 63, quad = lane >> 4, l16 = lane & 15;
  const int wmq = (wave >> 1) * 64;          // wave m-offset (4 quadrants)
  const int wnq = (wave & 1) * 64;           // wave n-offset (2 halves)
  const bool hi = (wave & 1);                // pacc covers acc rows 2*hi..2*hi+1
  const int bidx = m0 >> 11;
  const int i2 = n0 >> 8;                    // block-uniform lora index

  if (tid < 256) {
    const float4* src = (const float4*)(x + ((size_t)(bidx * 2048 + 10 + 2 * i2)) * DDIM);
    float4 v = src[tid];
    ushort4 o; o.x = f2bf(v.x); o.y = f2bf(v.y); o.z = f2bf(v.z); o.w = f2bf(v.w);
    ((ushort4*)od_lds)[tid] = o;
  }
  LKW();   // own od ds_write drained; prologue BAR publishes it

  f32x4 acc[4][4];
  const f32x4 z = {0.f, 0.f, 0.f, 0.f};
#pragma unroll
  for (int i = 0; i < 4; ++i)
#pragma unroll
    for (int j = 0; j < 4; ++j) acc[i][j] = z;
  f32x4 pacc[2] = {z, z};
  const bf16x8 zer8 = __builtin_bit_cast(bf16x8, z);

  const unsigned short *gA[4], *gB[2];
#pragma unroll
  for (int s = 0; s < 4; ++s) {
    int idx = (wave * 4 + s) * 64 + lane;
    int r = idx >> 3, sl = idx & 7, c = (sl - r) & 7;
    gA[s] = hact + (size_t)(m0 + r) * HDIM + c * 8;
  }
#pragma unroll
  for (int s = 0; s < 2; ++s) {
    int idx = (wave * 2 + s) * 64 + lane;
    int r = idx >> 3, sl = idx & 7, c = (sl - r) & 7;
    gB[s] = w2b + (size_t)(n0 + r) * HDIM + c * 8;
  }

#define STAGE2(tt, sb) do {                                   \
    const int _k = (tt) * 64;                                 \
    unsigned short* _a = &As[(sb) * 16384];                   \
    unsigned short* _b = &Bs[(sb) * 8192];                    \
    gld_lds16(gA[0] + _k, _a + (wave * 4 + 0) * 512);         \
    gld_lds16(gA[1] + _k, _a + (wave * 4 + 1) * 512);         \
    gld_lds16(gA[2] + _k, _a + (wave * 4 + 2) * 512);         \
    gld_lds16(gA[3] + _k, _a + (wave * 4 + 3) * 512);         \
    gld_lds16(gB[0] + _k, _b + (wave * 2 + 0) * 512);         \
    gld_lds16(gB[1] + _k, _b + (wave * 2 + 1) * 512);         \
  } while (0)

  bf16x8 a[4], b[4], odv;   // static-indexed everywhere

  auto RPH = [&](int nb, int kk, int odk) {
    const unsigned short* Ab = As + nb * 16384;
    const unsigned short* Bb = Bs + nb * 8192;
    odv = *(const bf16x8*)(od_lds + odk + kk + quad * 8);
    const int cb = (kk >> 3) + quad;
#pragma unroll
    for (int j = 0; j < 4; ++j) {
      const int rb = wnq + j * 16 + l16;
      b[j] = *(const bf16x8*)(Bb + rb * 64 + ((cb + rb) & 7) * 8);
    }
#pragma unroll
    for (int i = 0; i < 4; ++i) {
      const int ra = wmq + i * 16 + l16;
      a[i] = *(const bf16x8*)(Ab + ra * 64 + ((cb + ra) & 7) * 8);
    }
  };
  auto MPH = [&]() {
    bf16x8 bod = (l16 == 0) ? odv : zer8;
    bf16x8 pa0 = hi ? a[2] : a[0];
    bf16x8 pa1 = hi ? a[3] : a[1];
    pacc[0] = __builtin_amdgcn_mfma_f32_16x16x32_bf16(pa0, bod, pacc[0], 0, 0, 0);
    pacc[1] = __builtin_amdgcn_mfma_f32_16x16x32_bf16(pa1, bod, pacc[1], 0, 0, 0);
    __builtin_amdgcn_s_setprio(1);
#pragma unroll
    for (int i = 0; i < 4; ++i)
#pragma unroll
      for (int j = 0; j < 4; ++j)
        acc[i][j] = __builtin_amdgcn_mfma_f32_16x16x32_bf16(a[i], b[j], acc[i][j], 0, 0, 0);
    __builtin_amdgcn_s_setprio(0);
  };
  auto flush_p2 = [&](int seg) {
    const int ibase = hi ? 2 : 0;
    if (l16 == 0) {
#pragma unroll
      for (int ip = 0; ip < 2; ++ip)
#pragma unroll
        for (int e = 0; e < 4; ++e)
          p2s[(wmq + (ibase + ip) * 16 + quad * 4 + e) * 4 + seg] = pacc[ip][e];
    }
    pacc[0] = z; pacc[1] = z;
  };

#define G2BODY(tt, cb, sb, nb) do {                 \
    LKW(); MPH();                                   \
    RPH(cb, 32, ((tt) * 64) & 1023);                \
    STAGE2((tt) + 2, sb);                           \
    VMW(6);                                         \
    LKW(); MPH();                                   \
    if (((tt) & 15) == 15) flush_p2((tt) >> 4);     \
    BAR();                                          \
    RPH(nb, 0, (((tt) + 1) * 64) & 1023);           \
  } while (0)

  STAGE2(0, 0);
  STAGE2(1, 1);
  VMW(6); BAR();
  RPH(0, 0, 0);

#pragma unroll 1
  for (int t = 0; t < 60; t += 3) {     // bodies 0..59, stages 2..61
    G2BODY(t + 0, 0, 2, 1);
    G2BODY(t + 1, 1, 0, 2);
    G2BODY(t + 2, 2, 1, 0);
  }
  // t=60: stages 62
  LKW(); MPH(); RPH(0, 32, (60 * 64) & 1023); STAGE2(62, 2); VMW(6);
  LKW(); MPH(); BAR(); RPH(1, 0, (61 * 64) & 1023);
  // t=61: stages 63 (last)
  LKW(); MPH(); RPH(1, 32, (61 * 64) & 1023); STAGE2(63, 0); VMW(6);
  LKW(); MPH(); BAR(); RPH(2, 0, (62 * 64) & 1023);
  // t=62: confirm 63
  LKW(); MPH(); RPH(2, 32, (62 * 64) & 1023); VMW(0);
  LKW(); MPH(); BAR(); RPH(0, 0, (63 * 64) & 1023);
  // t=63: final
  LKW(); MPH(); RPH(0, 32, (63 * 64) & 1023);
  LKW(); MPH();
  flush_p2(3);
  LKW();
  BAR();

  const float sc = scale_p[0];
  const float* evrow = x + ((size_t)(bidx * 2048 + 9 + 2 * i2)) * DDIM;

  float4 ev[4]; float b2v[4]; int nn[4];
#pragma unroll
  for (int j = 0; j < 4; ++j) {
    nn[j] = n0 + wnq + j * 16 + l16;
    ev[j]  = *(const float4*)(evrow + 4 * (nn[j] & 255));
    b2v[j] = b2[nn[j]];
  }
#pragma unroll
  for (int i = 0; i < 4; ++i) {
#pragma unroll
    for (int r = 0; r < 4; ++r) {
      const int mloc = wmq + i * 16 + quad * 4 + r;
      const int m = m0 + mloc;
      const float4 pv = *(const float4*)(p2s + mloc * 4);
#pragma unroll
      for (int j = 0; j < 4; ++j) {
        float lora = ev[j].x * pv.x + ev[j].y * pv.y + ev[j].z * pv.z + ev[j].w * pv.w;
        out[(size_t)m * DDIM + nn[j]] = acc[i][j][r] + b2v[j] + sc * lora;
      }
    }
  }
#undef G2BODY
#undef STAGE2
}

extern "C" void kernel_launch(void* const* d_in, const int* in_sizes, int n_in,
                              void* d_out, int out_size, void* d_ws, size_t ws_size,
                              hipStream_t stream) {
  const float* x     = (const float*)d_in[0];
  const float* W1    = (const float*)d_in[1];
  const float* b1    = (const float*)d_in[2];
  const float* W2    = (const float*)d_in[3];
  const float* b2    = (const float*)d_in[4];
  const float* scale = (const float*)d_in[5];
  float* out = (float*)d_out;

  char* ws = (char*)d_ws;
  unsigned short* xb   = (unsigned short*)(ws);                // 16 MiB
  unsigned short* w1b  = (unsigned short*)(ws + 16777216);     //  8 MiB
  unsigned short* w2b  = (unsigned short*)(ws + 25165824);     //  8 MiB
  unsigned short* hact = (unsigned short*)(ws + 33554432);     // 64 MiB
  float*          p1   = (float*)(ws + 100663296);             // 128 KiB

  pre_kernel<<<dim3(2560), dim3(256), 0, stream>>>(x, W1, W2, xb, w1b, w2b, p1);
  gemm1_kernel<<<dim3(512), dim3(512), 0, stream>>>(xb, w1b, x, b1, p1, scale, hact);
  gemm2_kernel<<<dim3(256), dim3(512), 0, stream>>>(hact, w2b, x, b2, scale, out);
}

// Round 12
// 254.519 us; speedup vs baseline: 1.0593x; 1.0593x over previous
//
#include <hip/hip_runtime.h>
#include <cstdint>
#include <cstddef>

// Problem constants: B=4, S=2048, D=1024, H=4096, M = B*S = 8192.
#define MROWS 8192
#define DDIM  1024
#define HDIM  4096

typedef __bf16 bf16x8 __attribute__((ext_vector_type(8)));
typedef float  f32x4  __attribute__((ext_vector_type(4)));

typedef __attribute__((address_space(1))) void* as1_vp;
typedef __attribute__((address_space(3))) void* as3_vp;

__device__ __forceinline__ unsigned short f2bf(float f) {
  unsigned int u = __builtin_bit_cast(unsigned int, f);
  u += 0x7fffu + ((u >> 16) & 1u);   // RNE
  return (unsigned short)(u >> 16);
}

// fast gelu: tanh-form, exp2+rcp based. |err vs exact erf-gelu| < ~1e-3.
__device__ __forceinline__ float fast_gelu(float x) {
  float x3 = x * x * x;
  float z = 0.7978845608028654f * x + 0.03567740814f * x3;
  float e = __builtin_amdgcn_exp2f(z * 2.8853900817779268f); // exp(2z)
  float t = 1.0f - 2.0f * __builtin_amdgcn_rcpf(e + 1.0f);   // tanh(z)
  return 0.5f * x * (1.0f + t);
}

__device__ __forceinline__ void gld_lds16(const unsigned short* g, unsigned short* lds) {
  __builtin_amdgcn_global_load_lds((as1_vp)(uintptr_t)g, (as3_vp)lds, 16, 0, 0);
}

#define VMW(n)  asm volatile("s_waitcnt vmcnt(" #n ")" ::: "memory")
#define LKW()   asm volatile("s_waitcnt lgkmcnt(0)" ::: "memory")
#define BAR()   asm volatile("s_barrier" ::: "memory")

// pre_kernel v2 (R9): grid 2560. Blocks [0,2048): p1 + xb emit.
// Blocks [2048,2560): W1,W2 fp32->bf16, 16 float4/thread fully unrolled.
__global__ __launch_bounds__(256) void pre_kernel(
    const float* __restrict__ x, const float* __restrict__ w1,
    const float* __restrict__ w2, unsigned short* __restrict__ xb,
    unsigned short* __restrict__ w1b, unsigned short* __restrict__ w2b,
    float* __restrict__ p1) {
  if (blockIdx.x >= 2048) {
    const int j = blockIdx.x - 2048;           // 0..511
    const float4* src; ushort4* dst; int off0;
    if (j < 256) { src = (const float4*)w1; dst = (ushort4*)w1b; off0 = j * 4096 + threadIdx.x; }
    else         { src = (const float4*)w2; dst = (ushort4*)w2b; off0 = (j - 256) * 4096 + threadIdx.x; }
    float4 v[16];
#pragma unroll
    for (int k = 0; k < 16; ++k) v[k] = src[off0 + k * 256];
#pragma unroll
    for (int k = 0; k < 16; ++k) {
      ushort4 o;
      o.x = f2bf(v[k].x); o.y = f2bf(v[k].y); o.z = f2bf(v[k].z); o.w = f2bf(v[k].w);
      dst[off0 + k * 256] = o;
    }
    return;
  }
  const int bid = blockIdx.x;                  // 0..2047
  const int wave = threadIdx.x >> 6, lane = threadIdx.x & 63;
  const int m = bid * 4 + wave;
  const int b = m >> 11;
  const float4* xrow4 = (const float4*)(x + (size_t)m * DDIM);
  const float4* od4   = (const float4*)(x + ((size_t)b * 2048 + 2) * DDIM);
  ushort4* xbrow4 = (ushort4*)(xb + (size_t)m * DDIM);
  float a0 = 0.f, a1 = 0.f, a2 = 0.f, a3 = 0.f;
#pragma unroll
  for (int it = 0; it < 4; ++it) {
    int g = it * 64 + lane;
    float4 v = xrow4[g];
    ushort4 o; o.x = f2bf(v.x); o.y = f2bf(v.y); o.z = f2bf(v.z); o.w = f2bf(v.w);
    xbrow4[g] = o;
    float4 o0 = od4[g];
    float4 o1 = od4[512 + g];
    float4 o2 = od4[1024 + g];
    float4 o3 = od4[1536 + g];
    a0 += v.x * o0.x + v.y * o0.y + v.z * o0.z + v.w * o0.w;
    a1 += v.x * o1.x + v.y * o1.y + v.z * o1.z + v.w * o1.w;
    a2 += v.x * o2.x + v.y * o2.y + v.z * o2.z + v.w * o2.w;
    a3 += v.x * o3.x + v.y * o3.y + v.z * o3.z + v.w * o3.w;
  }
#pragma unroll
  for (int off = 32; off > 0; off >>= 1) {
    a0 += __shfl_down(a0, off);
    a1 += __shfl_down(a1, off);
    a2 += __shfl_down(a2, off);
    a3 += __shfl_down(a3, off);
  }
  if (lane == 0) {
    float4 r; r.x = a0; r.y = a1; r.z = a2; r.w = a3;
    ((float4*)p1)[m] = r;
  }
}

// ---------------------------------------------------------------------------
// GEMM1 (R4 structure, best measured 82.4us): 256x256, BK=32, ring-4 LDS,
// rotated body: LKW; MFA; RB(cb); STAGE(t+3); VMW(8); LKW; MFB; BAR; RA(nb).
// Counted vmcnt never 0 in loop; 1 barrier/tile. Proven-zero rotation
// swizzle: chunk c of row r at slot (c+(r>>1))&3.
// ---------------------------------------------------------------------------
__global__ __launch_bounds__(512, 2) void gemm1_kernel(
    const unsigned short* __restrict__ xb, const unsigned short* __restrict__ w1b,
    const float* __restrict__ x, const float* __restrict__ b1,
    const float* __restrict__ p1, const float* __restrict__ scale_p,
    unsigned short* __restrict__ hact) {
  __shared__ __align__(16) unsigned short As[4 * 256 * 32];   // 64 KB
  __shared__ __align__(16) unsigned short Bs[4 * 256 * 32];   // 64 KB

  const int id = blockIdx.x;                 // 512 blocks
  const int xcd = id & 7, w = id >> 3;       // XCD-contiguous m-bands
  const int m0 = (xcd * 4 + (w & 3)) * 256;  // 32 m-tiles
  const int n0 = (w >> 2) * 256;             // 16 n-tiles

  const int tid  = threadIdx.x;
  const int wave = tid >> 6, lane = tid & 63;
  const int quad = lane >> 4, l16 = lane & 15;
  const int wm2  = wave >> 2;                // 0..1 -> 128-row half
  const int wn2  = wave & 3;                 // 0..3 -> 64-col slice

  const unsigned short *gA0, *gA1, *gB0, *gB1;
  {
    int idx = tid;
    int r = idx >> 2, sl = idx & 3, c = (sl - (r >> 1)) & 3;
    gA0 = xb  + (size_t)(m0 + r) * DDIM + c * 8;
    gB0 = w1b + (size_t)(n0 + r) * DDIM + c * 8;
    idx = 512 + tid;
    r = idx >> 2; sl = idx & 3; c = (sl - (r >> 1)) & 3;
    gA1 = xb  + (size_t)(m0 + r) * DDIM + c * 8;
    gB1 = w1b + (size_t)(n0 + r) * DDIM + c * 8;
  }
  const int ldsOff0 = (wave * 64) * 8;         // wave-uniform halfword offsets
  const int ldsOff1 = (512 + wave * 64) * 8;

#define STAGE1(tt, sb) do {                                   \
    const int _k = (tt) * 32;                                 \
    unsigned short* _a = &As[(sb) * 8192];                    \
    unsigned short* _b = &Bs[(sb) * 8192];                    \
    gld_lds16(gA0 + _k, _a + ldsOff0);                        \
    gld_lds16(gA1 + _k, _a + ldsOff1);                        \
    gld_lds16(gB0 + _k, _b + ldsOff0);                        \
    gld_lds16(gB1 + _k, _b + ldsOff1);                        \
  } while (0)

  f32x4 acc[8][4];
  const f32x4 z = {0.f, 0.f, 0.f, 0.f};
#pragma unroll
  for (int i = 0; i < 8; ++i)
#pragma unroll
    for (int j = 0; j < 4; ++j) acc[i][j] = z;

  bf16x8 a[8], b[4];   // static-indexed everywhere (rule #20)

  auto RA = [&](int nb) {          // a[0..3], b[0..3] from buf nb
    const unsigned short* Ab = As + nb * 8192;
    const unsigned short* Bb = Bs + nb * 8192;
#pragma unroll
    for (int j = 0; j < 4; ++j) {
      const int rb = wn2 * 64 + j * 16 + l16;
      b[j] = *(const bf16x8*)(Bb + rb * 32 + ((quad + (rb >> 1)) & 3) * 8);
    }
#pragma unroll
    for (int i = 0; i < 4; ++i) {
      const int ra = wm2 * 128 + i * 16 + l16;
      a[i] = *(const bf16x8*)(Ab + ra * 32 + ((quad + (ra >> 1)) & 3) * 8);
    }
  };
  auto RB = [&](int cb) {          // a[4..7] from buf cb
    const unsigned short* Ab = As + cb * 8192;
#pragma unroll
    for (int i = 4; i < 8; ++i) {
      const int ra = wm2 * 128 + i * 16 + l16;
      a[i] = *(const bf16x8*)(Ab + ra * 32 + ((quad + (ra >> 1)) & 3) * 8);
    }
  };
  auto MFA = [&]() {
    __builtin_amdgcn_s_setprio(1);
#pragma unroll
    for (int i = 0; i < 4; ++i)
#pragma unroll
      for (int j = 0; j < 4; ++j)
        acc[i][j] = __builtin_amdgcn_mfma_f32_16x16x32_bf16(a[i], b[j], acc[i][j], 0, 0, 0);
    __builtin_amdgcn_s_setprio(0);
  };
  auto MFB = [&]() {
    __builtin_amdgcn_s_setprio(1);
#pragma unroll
    for (int i = 4; i < 8; ++i)
#pragma unroll
      for (int j = 0; j < 4; ++j)
        acc[i][j] = __builtin_amdgcn_mfma_f32_16x16x32_bf16(a[i], b[j], acc[i][j], 0, 0, 0);
    __builtin_amdgcn_s_setprio(0);
  };

#define G1BODY(cb, sb, nb, tt) do {   \
    LKW(); MFA();                     \
    RB(cb);                           \
    STAGE1((tt) + 3, sb);             \
    VMW(8);                           \
    LKW(); MFB();                     \
    BAR();                            \
    RA(nb);                           \
  } while (0)

  // Prologue: tiles 0,1,2 in flight (12 loads/wave), confirm 0, read its frags.
  STAGE1(0, 0);
  STAGE1(1, 1);
  STAGE1(2, 2);
  VMW(8); BAR();
  RA(0);

#pragma unroll 1
  for (int t = 0; t < 28; t += 4) {   // bodies 0..27, stages 3..30
    G1BODY(0, 3, 1, t + 0);
    G1BODY(1, 0, 2, t + 1);
    G1BODY(2, 1, 3, t + 2);
    G1BODY(3, 2, 0, t + 3);
  }
  // t=28: stages 31 (last)
  LKW(); MFA(); RB(0); STAGE1(31, 3); VMW(8); LKW(); MFB(); BAR(); RA(1);
  // t=29: confirm 30
  LKW(); MFA(); RB(1); VMW(4); LKW(); MFB(); BAR(); RA(2);
  // t=30: confirm 31
  LKW(); MFA(); RB(2); VMW(0); LKW(); MFB(); BAR(); RA(3);
  // t=31: final
  LKW(); MFA(); RB(3); LKW(); MFB();

  const float sc = scale_p[0];
  const int bidx = m0 >> 11;
  const int i1 = (n0 + wn2 * 64) >> 10;      // wave-uniform lora index
  const float* exrow = x + ((size_t)(bidx * 2048 + 1 + 2 * i1)) * DDIM;

  float exv[4], b1v[4]; int nn[4];
#pragma unroll
  for (int j = 0; j < 4; ++j) {
    nn[j]  = n0 + wn2 * 64 + j * 16 + l16;
    exv[j] = exrow[nn[j] & 1023];
    b1v[j] = b1[nn[j]];
  }
#pragma unroll
  for (int i = 0; i < 8; ++i) {
#pragma unroll
    for (int r = 0; r < 4; ++r) {
      const int m = m0 + wm2 * 128 + i * 16 + quad * 4 + r;
      const float pv = p1[(size_t)m * 4 + i1] * sc;
#pragma unroll
      for (int j = 0; j < 4; ++j) {
        float v = acc[i][j][r] + b1v[j] + pv * exv[j];
        hact[(size_t)m * HDIM + nn[j]] = f2bf(fast_gelu(v));
      }
    }
  }
#undef G1BODY
#undef STAGE1
}

// ---------------------------------------------------------------------------
// GEMM2 (R4 structure, best measured 82.3us): 256m x 128n, BK=64, ring-3,
// rotated 2-phase body, counted VMW(6), 1 barrier/tile. p2 fused on matrix
// pipe (static-index wave-uniform selects — rule #20).
// ---------------------------------------------------------------------------
__global__ __launch_bounds__(512, 2) void gemm2_kernel(
    const unsigned short* __restrict__ hact, const unsigned short* __restrict__ w2b,
    const float* __restrict__ x, const float* __restrict__ b2,
    const float* __restrict__ scale_p, float* __restrict__ out) {
  __shared__ __align__(16) unsigned short As[3 * 256 * 64];   // 96 KB
  __shared__ __align__(16) unsigned short Bs[3 * 128 * 64];   // 48 KB
  __shared__ __align__(16) unsigned short od_lds[1024];       // 2 KB
  __shared__ __align__(16) float p2s[256 * 4];                // 4 KB

  const int id = blockIdx.x;                 // 256 blocks = 1/CU
  const int xcd = id & 7, w = id >> 3;       // 32 blocks per XCD
  const int m0 = (xcd * 4 + (w & 3)) * 256;  // 32 m-tiles
  const int n0 = (w >> 2) * 128;             // 8 n-tiles
  const int tid = threadIdx.x;
  const int wave = tid >> 6, lane = tid & 63, quad = lane >> 4, l16 = lane & 15;
  const int wmq = (wave >> 1) * 64;          // wave m-offset (4 quadrants)
  const int wnq = (wave & 1) * 64;           // wave n-offset (2 halves)
  const bool hi = (wave & 1);                // pacc covers acc rows 2*hi..2*hi+1
  const int bidx = m0 >> 11;
  const int i2 = n0 >> 8;                    // block-uniform lora index

  if (tid < 256) {
    const float4* src = (const float4*)(x + ((size_t)(bidx * 2048 + 10 + 2 * i2)) * DDIM);
    float4 v = src[tid];
    ushort4 o; o.x = f2bf(v.x); o.y = f2bf(v.y); o.z = f2bf(v.z); o.w = f2bf(v.w);
    ((ushort4*)od_lds)[tid] = o;
  }
  LKW();   // own od ds_write drained; prologue BAR publishes it

  f32x4 acc[4][4];
  const f32x4 z = {0.f, 0.f, 0.f, 0.f};
#pragma unroll
  for (int i = 0; i < 4; ++i)
#pragma unroll
    for (int j = 0; j < 4; ++j) acc[i][j] = z;
  f32x4 pacc[2] = {z, z};
  const bf16x8 zer8 = __builtin_bit_cast(bf16x8, z);

  const unsigned short *gA[4], *gB[2];
#pragma unroll
  for (int s = 0; s < 4; ++s) {
    int idx = (wave * 4 + s) * 64 + lane;
    int r = idx >> 3, sl = idx & 7, c = (sl - r) & 7;
    gA[s] = hact + (size_t)(m0 + r) * HDIM + c * 8;
  }
#pragma unroll
  for (int s = 0; s < 2; ++s) {
    int idx = (wave * 2 + s) * 64 + lane;
    int r = idx >> 3, sl = idx & 7, c = (sl - r) & 7;
    gB[s] = w2b + (size_t)(n0 + r) * HDIM + c * 8;
  }

#define STAGE2(tt, sb) do {                                   \
    const int _k = (tt) * 64;                                 \
    unsigned short* _a = &As[(sb) * 16384];                   \
    unsigned short* _b = &Bs[(sb) * 8192];                    \
    gld_lds16(gA[0] + _k, _a + (wave * 4 + 0) * 512);         \
    gld_lds16(gA[1] + _k, _a + (wave * 4 + 1) * 512);         \
    gld_lds16(gA[2] + _k, _a + (wave * 4 + 2) * 512);         \
    gld_lds16(gA[3] + _k, _a + (wave * 4 + 3) * 512);         \
    gld_lds16(gB[0] + _k, _b + (wave * 2 + 0) * 512);         \
    gld_lds16(gB[1] + _k, _b + (wave * 2 + 1) * 512);         \
  } while (0)

  bf16x8 a[4], b[4], odv;   // static-indexed everywhere

  auto RPH = [&](int nb, int kk, int odk) {
    const unsigned short* Ab = As + nb * 16384;
    const unsigned short* Bb = Bs + nb * 8192;
    odv = *(const bf16x8*)(od_lds + odk + kk + quad * 8);
    const int cb = (kk >> 3) + quad;
#pragma unroll
    for (int j = 0; j < 4; ++j) {
      const int rb = wnq + j * 16 + l16;
      b[j] = *(const bf16x8*)(Bb + rb * 64 + ((cb + rb) & 7) * 8);
    }
#pragma unroll
    for (int i = 0; i < 4; ++i) {
      const int ra = wmq + i * 16 + l16;
      a[i] = *(const bf16x8*)(Ab + ra * 64 + ((cb + ra) & 7) * 8);
    }
  };
  auto MPH = [&]() {
    bf16x8 bod = (l16 == 0) ? odv : zer8;
    bf16x8 pa0 = hi ? a[2] : a[0];
    bf16x8 pa1 = hi ? a[3] : a[1];
    pacc[0] = __builtin_amdgcn_mfma_f32_16x16x32_bf16(pa0, bod, pacc[0], 0, 0, 0);
    pacc[1] = __builtin_amdgcn_mfma_f32_16x16x32_bf16(pa1, bod, pacc[1], 0, 0, 0);
    __builtin_amdgcn_s_setprio(1);
#pragma unroll
    for (int i = 0; i < 4; ++i)
#pragma unroll
      for (int j = 0; j < 4; ++j)
        acc[i][j] = __builtin_amdgcn_mfma_f32_16x16x32_bf16(a[i], b[j], acc[i][j], 0, 0, 0);
    __builtin_amdgcn_s_setprio(0);
  };
  auto flush_p2 = [&](int seg) {
    const int ibase = hi ? 2 : 0;
    if (l16 == 0) {
#pragma unroll
      for (int ip = 0; ip < 2; ++ip)
#pragma unroll
        for (int e = 0; e < 4; ++e)
          p2s[(wmq + (ibase + ip) * 16 + quad * 4 + e) * 4 + seg] = pacc[ip][e];
    }
    pacc[0] = z; pacc[1] = z;
  };

#define G2BODY(tt, cb, sb, nb) do {                 \
    LKW(); MPH();                                   \
    RPH(cb, 32, ((tt) * 64) & 1023);                \
    STAGE2((tt) + 2, sb);                           \
    VMW(6);                                         \
    LKW(); MPH();                                   \
    if (((tt) & 15) == 15) flush_p2((tt) >> 4);     \
    BAR();                                          \
    RPH(nb, 0, (((tt) + 1) * 64) & 1023);           \
  } while (0)

  STAGE2(0, 0);
  STAGE2(1, 1);
  VMW(6); BAR();
  RPH(0, 0, 0);

#pragma unroll 1
  for (int t = 0; t < 60; t += 3) {     // bodies 0..59, stages 2..61
    G2BODY(t + 0, 0, 2, 1);
    G2BODY(t + 1, 1, 0, 2);
    G2BODY(t + 2, 2, 1, 0);
  }
  // t=60: stages 62
  LKW(); MPH(); RPH(0, 32, (60 * 64) & 1023); STAGE2(62, 2); VMW(6);
  LKW(); MPH(); BAR(); RPH(1, 0, (61 * 64) & 1023);
  // t=61: stages 63 (last)
  LKW(); MPH(); RPH(1, 32, (61 * 64) & 1023); STAGE2(63, 0); VMW(6);
  LKW(); MPH(); BAR(); RPH(2, 0, (62 * 64) & 1023);
  // t=62: confirm 63
  LKW(); MPH(); RPH(2, 32, (62 * 64) & 1023); VMW(0);
  LKW(); MPH(); BAR(); RPH(0, 0, (63 * 64) & 1023);
  // t=63: final
  LKW(); MPH(); RPH(0, 32, (63 * 64) & 1023);
  LKW(); MPH();
  flush_p2(3);
  LKW();
  BAR();

  const float sc = scale_p[0];
  const float* evrow = x + ((size_t)(bidx * 2048 + 9 + 2 * i2)) * DDIM;

  float4 ev[4]; float b2v[4]; int nn[4];
#pragma unroll
  for (int j = 0; j < 4; ++j) {
    nn[j] = n0 + wnq + j * 16 + l16;
    ev[j]  = *(const float4*)(evrow + 4 * (nn[j] & 255));
    b2v[j] = b2[nn[j]];
  }
#pragma unroll
  for (int i = 0; i < 4; ++i) {
#pragma unroll
    for (int r = 0; r < 4; ++r) {
      const int mloc = wmq + i * 16 + quad * 4 + r;
      const int m = m0 + mloc;
      const float4 pv = *(const float4*)(p2s + mloc * 4);
#pragma unroll
      for (int j = 0; j < 4; ++j) {
        float lora = ev[j].x * pv.x + ev[j].y * pv.y + ev[j].z * pv.z + ev[j].w * pv.w;
        out[(size_t)m * DDIM + nn[j]] = acc[i][j][r] + b2v[j] + sc * lora;
      }
    }
  }
#undef G2BODY
#undef STAGE2
}

extern "C" void kernel_launch(void* const* d_in, const int* in_sizes, int n_in,
                              void* d_out, int out_size, void* d_ws, size_t ws_size,
                              hipStream_t stream) {
  const float* x     = (const float*)d_in[0];
  const float* W1    = (const float*)d_in[1];
  const float* b1    = (const float*)d_in[2];
  const float* W2    = (const float*)d_in[3];
  const float* b2    = (const float*)d_in[4];
  const float* scale = (const float*)d_in[5];
  float* out = (float*)d_out;

  char* ws = (char*)d_ws;
  unsigned short* xb   = (unsigned short*)(ws);                // 16 MiB
  unsigned short* w1b  = (unsigned short*)(ws + 16777216);     //  8 MiB
  unsigned short* w2b  = (unsigned short*)(ws + 25165824);     //  8 MiB
  unsigned short* hact = (unsigned short*)(ws + 33554432);     // 64 MiB
  float*          p1   = (float*)(ws + 100663296);             // 128 KiB

  pre_kernel<<<dim3(2560), dim3(256), 0, stream>>>(x, W1, W2, xb, w1b, w2b, p1);
  gemm1_kernel<<<dim3(512), dim3(512), 0, stream>>>(xb, w1b, x, b1, p1, scale, hact);
  gemm2_kernel<<<dim3(256), dim3(512), 0, stream>>>(hact, w2b, x, b2, scale, out);
}